// Round 2
// baseline (550.819 us; speedup 1.0000x reference)
//
#include <hip/hip_runtime.h>
#include <math.h>

#define BATCH  8192
#define D_IN   592
#define FBANKS 8
#define P1     147   // pool1 output length
#define P2     36    // pool2 output length
#define P1PAD  152   // padded row (16B-multiple stride, room for b128 over-read)
#define NW     4     // waves (rows) per block
#define PLANE  ((size_t)BATCH * D_IN)   // elems per (bank) slab within one output

// Wave-synchronous ordering: CDNA waves are lockstep (one PC + exec mask) and
// DS ops complete in program order per wave, so producer->consumer through
// per-wave LDS scratch needs only a compiler reordering fence, not s_barrier.
#define WAVE_SYNC() do { __builtin_amdgcn_wave_barrier(); asm volatile("" ::: "memory"); } while (0)

// Structure: PHASE 1 runs the serial conv/MLP chain for all 8 banks, producing
// only f0[8] per row (plus the xa recurrence in LDS) -- zero wide stores.
// PHASE 2 replays the Gaussian recurrence from x + f0[8] in registers and
// issues all 466 MB of output stores back-to-back at full HBM rate.
// Rationale: in the fused form all waves are in structural lockstep, so chain
// phases (HBM idle) and store bursts (HBM saturated) serialize grid-wide,
// capping effective BW at ~2.5 TB/s. Concentrating the stores makes phase 2
// behave like the harness fill, which measures 6.2 TB/s on this buffer.

__global__ __launch_bounds__(256, 6) void fb_kernel(
    const float* __restrict__ x,
    const float* __restrict__ c1w, const float* __restrict__ c1b,
    const float* __restrict__ c2w, const float* __restrict__ c2b,
    const float* __restrict__ l1w, const float* __restrict__ l1b,
    const float* __restrict__ l2w, const float* __restrict__ l2b,
    const float* __restrict__ l3w, const float* __restrict__ l3b,
    float* __restrict__ outH, float* __restrict__ outXF,
    float* __restrict__ outXS, float* __restrict__ outF0)
{
    // ---- per-wave scratch only (no cross-wave sharing -> no __syncthreads) ----
    __shared__ __align__(16) float s_xa[NW][D_IN];
    __shared__ __align__(16) float s_p1[NW][3][P1PAD];
    __shared__ __align__(16) float s_p2[NW][40];
    __shared__ __align__(16) float s_l1o[NW][20];
    __shared__ __align__(16) float s_f0[NW][8];
    // LDS/block = 17,856 B

    const int tid  = threadIdx.x;
    const int wave = tid >> 6;
    const int lane = tid & 63;
    const int row  = blockIdx.x * NW + wave;

    float* xa = s_xa[wave];
    const float* xrow = x + (size_t)row * D_IN;
    for (int i = lane; i < 148; i += 64) {               // 148 float4 = 592 floats
        *(float4*)&xa[4 * i] = *(const float4*)&xrow[4 * i];
    }
    WAVE_SYNC();

    // Gaussian: H = exp(-d^2/(2w^2)) = exp2(d^2 * negc2), w=5
    const float negc2 = -0.028853900817779268f;   // -log2(e)/50

    // ================= PHASE 1: chain only, produce f0[0..7] =================
    for (int bank = 0; bank < FBANKS; ++bank) {
        // ---- wave-uniform weights -> SGPRs (s_load, scalar cache) ----
        float w1[3][3], b1[3], w2[3][3];
        #pragma unroll
        for (int c = 0; c < 3; ++c) {
            b1[c] = c1b[bank * 3 + c];
            #pragma unroll
            for (int k = 0; k < 3; ++k) {
                w1[c][k] = c1w[bank * 9 + c * 3 + k];
                w2[c][k] = c2w[bank * 9 + c * 3 + k];
            }
        }
        const float b2 = c2b[bank];

        // ---- conv1(k3,s2)+maxpool(3,2)+relu: pooled p covers x[4p..4p+6] ----
        for (int p = lane; p < P1; p += 64) {
            float4 a = *(const float4*)&xa[4 * p];       // 4p..4p+3
            float4 b = *(const float4*)&xa[4 * p + 4];   // 4p+4..4p+7 (max 591)
            float xv0 = a.x, xv1 = a.y, xv2 = a.z, xv3 = a.w;
            float xv4 = b.x, xv5 = b.y, xv6 = b.z;
            #pragma unroll
            for (int c = 0; c < 3; ++c) {
                float v0 = w1[c][0] * xv0 + w1[c][1] * xv1 + w1[c][2] * xv2;
                float v1 = w1[c][0] * xv2 + w1[c][1] * xv3 + w1[c][2] * xv4;
                float v2 = w1[c][0] * xv4 + w1[c][1] * xv5 + w1[c][2] * xv6;
                float m  = fmaxf(fmaxf(v0, v1), v2) + b1[c];
                s_p1[wave][c][p] = fmaxf(m, 0.0f);
            }
        }
        WAVE_SYNC();

        // ---- conv2(3ch->1,k3,s2)+maxpool(3,2)+relu ----
        if (lane < P2) {
            const int q = lane;
            float acc0 = b2, acc1 = b2, acc2 = b2;
            #pragma unroll
            for (int c = 0; c < 3; ++c) {
                const float* r = s_p1[wave][c];
                float4 a = *(const float4*)&r[4 * q];
                float4 b = *(const float4*)&r[4 * q + 4];
                float v0 = a.x, v1 = a.y, v2 = a.z, v3 = a.w, v4 = b.x, v5 = b.y, v6 = b.z;
                acc0 += w2[c][0] * v0 + w2[c][1] * v1 + w2[c][2] * v2;
                acc1 += w2[c][0] * v2 + w2[c][1] * v3 + w2[c][2] * v4;
                acc2 += w2[c][0] * v4 + w2[c][1] * v5 + w2[c][2] * v6;
            }
            float mm = fmaxf(fmaxf(acc0, acc1), acc2);
            s_p2[wave][q] = fmaxf(mm, 0.0f);
        }
        WAVE_SYNC();

        // ---- lin1: 36 -> 20, relu (weights from global: L1-resident) ----
        if (lane < 20) {
            const float4* wr = (const float4*)(l1w + bank * 720 + lane * 36);
            float acc = l1b[bank * 20 + lane];
            #pragma unroll
            for (int k = 0; k < 9; ++k) {
                float4 w = wr[k];
                float4 v = *(const float4*)&s_p2[wave][4 * k];   // broadcast read
                acc += w.x * v.x + w.y * v.y + w.z * v.z + w.w * v.w;
            }
            s_l1o[wave][lane] = fmaxf(acc, 0.0f);
        }
        WAVE_SYNC();

        // ---- lin2 (20->10, relu) fused with lin3 (10->1) via shuffle reduce ----
        float part = 0.0f;
        if (lane < 10) {
            const float4* wr = (const float4*)(l2w + bank * 200 + lane * 20);
            float acc = l2b[bank * 10 + lane];
            #pragma unroll
            for (int k = 0; k < 5; ++k) {
                float4 w = wr[k];
                float4 v = *(const float4*)&s_l1o[wave][4 * k];  // broadcast read
                acc += w.x * v.x + w.y * v.y + w.z * v.z + w.w * v.w;
            }
            part = fmaxf(acc, 0.0f) * l3w[bank * 10 + lane];     // fold lin3 weight
        }
        // sum over lanes 0..9 (others contribute 0); xor-tree within 16-lane group
        part += __shfl_xor(part, 1);
        part += __shfl_xor(part, 2);
        part += __shfl_xor(part, 4);
        part += __shfl_xor(part, 8);
        float acc3 = __uint_as_float(__builtin_amdgcn_readfirstlane(__float_as_uint(part)))
                   + l3b[bank];
        float sig  = 1.0f / (1.0f + __expf(-acc3));
        float f0v  = (float)D_IN * sig;
        if (lane == 0) {
            s_f0[wave][bank] = f0v;
            outF0[(size_t)bank * BATCH + row] = f0v;
        }

        // ---- xa recurrence update in LDS only (no global stores);
        //      bank 7's update is dead -> skip entirely ----
        if (bank < FBANKS - 1) {
            for (int i = lane; i < 148; i += 64) {
                float4 xv = *(const float4*)&xa[4 * i];
                float d0 = (float)(4 * i) - f0v;
                float d1 = d0 + 1.0f, d2 = d0 + 2.0f, d3 = d0 + 3.0f;
                float4 Hv, xf;
                Hv.x = __builtin_amdgcn_exp2f(d0 * d0 * negc2);
                Hv.y = __builtin_amdgcn_exp2f(d1 * d1 * negc2);
                Hv.z = __builtin_amdgcn_exp2f(d2 * d2 * negc2);
                Hv.w = __builtin_amdgcn_exp2f(d3 * d3 * negc2);
                xf.x = xv.x * Hv.x;  xf.y = xv.y * Hv.y;
                xf.z = xv.z * Hv.z;  xf.w = xv.w * Hv.w;
                float4 xn;
                xn.x = xv.x - xf.x;  xn.y = xv.y - xf.y;
                xn.z = xv.z - xf.z;  xn.w = xv.w - xf.w;
                *(float4*)&xa[4 * i] = xn;
            }
        }
        WAVE_SYNC();
    }

    // ============ PHASE 2: pure streaming replay at full HBM rate ============
    float f0s[FBANKS];
    #pragma unroll
    for (int b = 0; b < FBANKS; ++b) f0s[b] = s_f0[wave][b];
    const size_t rowoff = (size_t)row * D_IN;

    for (int i = lane; i < 148; i += 64) {
        float4 xv = *(const float4*)&xrow[4 * i];        // L2/L3-warm re-read
        const float e0 = (float)(4 * i);
        #pragma unroll
        for (int b = 0; b < FBANKS; ++b) {
            const size_t off = (size_t)b * PLANE + rowoff + 4 * i;
            float d0 = e0 - f0s[b];
            float d1 = d0 + 1.0f, d2 = d0 + 2.0f, d3 = d0 + 3.0f;
            float4 Hv, xf;
            Hv.x = __builtin_amdgcn_exp2f(d0 * d0 * negc2);
            Hv.y = __builtin_amdgcn_exp2f(d1 * d1 * negc2);
            Hv.z = __builtin_amdgcn_exp2f(d2 * d2 * negc2);
            Hv.w = __builtin_amdgcn_exp2f(d3 * d3 * negc2);
            xf.x = xv.x * Hv.x;  xf.y = xv.y * Hv.y;
            xf.z = xv.z * Hv.z;  xf.w = xv.w * Hv.w;
            *(float4*)&outXS[off] = xv;                  // x_aux BEFORE filtering
            *(float4*)&outH [off] = Hv;
            *(float4*)&outXF[off] = xf;
            xv.x -= xf.x;  xv.y -= xf.y;
            xv.z -= xf.z;  xv.w -= xf.w;                 // next bank's x_aux
        }
    }
}

extern "C" void kernel_launch(void* const* d_in, const int* in_sizes, int n_in,
                              void* d_out, int out_size, void* d_ws, size_t ws_size,
                              hipStream_t stream) {
    const float* x   = (const float*)d_in[0];
    const float* c1w = (const float*)d_in[1];
    const float* c1b = (const float*)d_in[2];
    const float* c2w = (const float*)d_in[3];
    const float* c2b = (const float*)d_in[4];
    const float* l1w = (const float*)d_in[5];
    const float* l1b = (const float*)d_in[6];
    const float* l2w = (const float*)d_in[7];
    const float* l2b = (const float*)d_in[8];
    const float* l3w = (const float*)d_in[9];
    const float* l3b = (const float*)d_in[10];

    float* out = (float*)d_out;
    const size_t plane = (size_t)FBANKS * BATCH * D_IN;
    float* outH  = out;
    float* outXF = out + plane;
    float* outXS = out + 2 * plane;
    float* outF0 = out + 3 * plane;

    dim3 grid(BATCH / NW);
    dim3 block(256);
    fb_kernel<<<grid, block, 0, stream>>>(x, c1w, c1b, c2w, c2b,
                                          l1w, l1b, l2w, l2b, l3w, l3b,
                                          outH, outXF, outXS, outF0);
}

// Round 3
// 499.834 us; speedup vs baseline: 1.1020x; 1.1020x over previous
//
#include <hip/hip_runtime.h>
#include <math.h>

#define BATCH  8192
#define D_IN   592
#define FBANKS 8
#define P1     147   // pool1 output length
#define P2     36    // pool2 output length
#define P1PAD  152   // padded row (16B-multiple stride, room for b128 over-read)
#define NW     4     // waves (rows) per block

// Wave-synchronous ordering: CDNA waves are lockstep (one PC + exec mask) and
// DS ops complete in program order per wave, so producer->consumer through
// per-wave LDS scratch needs only a compiler reordering fence, not s_barrier.
#define WAVE_SYNC() do { __builtin_amdgcn_wave_barrier(); asm volatile("" ::: "memory"); } while (0)

// Store-side theory (R0/R1/R2 evidence): fused=202us, split=252us =>
// chain ~50us (hidden), stores ~200us @2.3TB/s in ANY per-wave layout.
// Root cause candidate: row stride 2368B = 18.5 cache lines, so odd rows'
// 1KB wave-stores are 64B-misaligned => 2 partial 128B lines per store
// (RMW at TCC), plus 24 interleaved streams/wave. The 6.2TB/s fill is one
// monotonic aligned stream with FETCH~0.
// Fix: block-cooperative sweep. Stage H in LDS (s_xa already holds XS);
// all 256 threads emit 3 monotonic 128B-aligned nontemporal streams per
// bank (block slab = 4 rows x 2368B = 9472B = 74 full lines).

typedef float f4v __attribute__((ext_vector_type(4)));
static __device__ __forceinline__ void nt_store4(float* p, float a, float b,
                                                 float c, float d) {
    f4v t = {a, b, c, d};
    __builtin_nontemporal_store(t, (f4v*)p);
}

__global__ __launch_bounds__(256, 5) void fb_kernel(
    const float* __restrict__ x,
    const float* __restrict__ c1w, const float* __restrict__ c1b,
    const float* __restrict__ c2w, const float* __restrict__ c2b,
    const float* __restrict__ l1w, const float* __restrict__ l1b,
    const float* __restrict__ l2w, const float* __restrict__ l2b,
    const float* __restrict__ l3w, const float* __restrict__ l3b,
    float* __restrict__ outH, float* __restrict__ outXF,
    float* __restrict__ outXS, float* __restrict__ outF0)
{
    __shared__ __align__(16) float s_xa[NW][D_IN];        // 9472 B (= XS staging)
    __shared__ __align__(16) float s_oH[NW][D_IN];        // 9472 B (H staging)
    __shared__ __align__(16) float s_p1[NW][3][P1PAD];
    __shared__ __align__(16) float s_p2[NW][40];
    __shared__ __align__(16) float s_l1o[NW][20];
    // LDS/block = 27.2 KB -> 5 blocks/CU

    const int tid  = threadIdx.x;
    const int wave = tid >> 6;
    const int lane = tid & 63;
    const int row  = blockIdx.x * NW + wave;
    const size_t blkrow = (size_t)blockIdx.x * NW;

    float* xa = s_xa[wave];
    const float* xrow = x + (size_t)row * D_IN;
    for (int i = lane; i < 148; i += 64) {               // 148 float4 = 592 floats
        *(float4*)&xa[4 * i] = *(const float4*)&xrow[4 * i];
    }
    WAVE_SYNC();   // wave-local use next; block-wide visibility covered by the
                   // __syncthreads before the first cooperative sweep

    // Gaussian: H = exp(-d^2/(2w^2)) = exp2(d^2 * negc2), w=5
    const float negc2 = -0.028853900817779268f;   // -log2(e)/50

    for (int bank = 0; bank < FBANKS; ++bank) {
        // ---- wave-uniform weights -> SGPRs (s_load, scalar cache) ----
        float w1[3][3], b1[3], w2[3][3];
        #pragma unroll
        for (int c = 0; c < 3; ++c) {
            b1[c] = c1b[bank * 3 + c];
            #pragma unroll
            for (int k = 0; k < 3; ++k) {
                w1[c][k] = c1w[bank * 9 + c * 3 + k];
                w2[c][k] = c2w[bank * 9 + c * 3 + k];
            }
        }
        const float b2 = c2b[bank];

        // ---- conv1(k3,s2)+maxpool(3,2)+relu: pooled p covers x[4p..4p+6] ----
        for (int p = lane; p < P1; p += 64) {
            float4 a = *(const float4*)&xa[4 * p];
            float4 b = *(const float4*)&xa[4 * p + 4];
            float xv0 = a.x, xv1 = a.y, xv2 = a.z, xv3 = a.w;
            float xv4 = b.x, xv5 = b.y, xv6 = b.z;
            #pragma unroll
            for (int c = 0; c < 3; ++c) {
                float v0 = w1[c][0] * xv0 + w1[c][1] * xv1 + w1[c][2] * xv2;
                float v1 = w1[c][0] * xv2 + w1[c][1] * xv3 + w1[c][2] * xv4;
                float v2 = w1[c][0] * xv4 + w1[c][1] * xv5 + w1[c][2] * xv6;
                float m  = fmaxf(fmaxf(v0, v1), v2) + b1[c];
                s_p1[wave][c][p] = fmaxf(m, 0.0f);
            }
        }
        WAVE_SYNC();

        // ---- conv2(3ch->1,k3,s2)+maxpool(3,2)+relu ----
        if (lane < P2) {
            const int q = lane;
            float acc0 = b2, acc1 = b2, acc2 = b2;
            #pragma unroll
            for (int c = 0; c < 3; ++c) {
                const float* r = s_p1[wave][c];
                float4 a = *(const float4*)&r[4 * q];
                float4 b = *(const float4*)&r[4 * q + 4];
                float v0 = a.x, v1 = a.y, v2 = a.z, v3 = a.w, v4 = b.x, v5 = b.y, v6 = b.z;
                acc0 += w2[c][0] * v0 + w2[c][1] * v1 + w2[c][2] * v2;
                acc1 += w2[c][0] * v2 + w2[c][1] * v3 + w2[c][2] * v4;
                acc2 += w2[c][0] * v4 + w2[c][1] * v5 + w2[c][2] * v6;
            }
            float mm = fmaxf(fmaxf(acc0, acc1), acc2);
            s_p2[wave][q] = fmaxf(mm, 0.0f);
        }
        WAVE_SYNC();

        // ---- lin1: 36 -> 20, relu (weights from global: L1-resident) ----
        if (lane < 20) {
            const float4* wr = (const float4*)(l1w + bank * 720 + lane * 36);
            float acc = l1b[bank * 20 + lane];
            #pragma unroll
            for (int k = 0; k < 9; ++k) {
                float4 w = wr[k];
                float4 v = *(const float4*)&s_p2[wave][4 * k];
                acc += w.x * v.x + w.y * v.y + w.z * v.z + w.w * v.w;
            }
            s_l1o[wave][lane] = fmaxf(acc, 0.0f);
        }
        WAVE_SYNC();

        // ---- lin2 (20->10, relu) fused with lin3 (10->1) via shuffle reduce ----
        float part = 0.0f;
        if (lane < 10) {
            const float4* wr = (const float4*)(l2w + bank * 200 + lane * 20);
            float acc = l2b[bank * 10 + lane];
            #pragma unroll
            for (int k = 0; k < 5; ++k) {
                float4 w = wr[k];
                float4 v = *(const float4*)&s_l1o[wave][4 * k];
                acc += w.x * v.x + w.y * v.y + w.z * v.z + w.w * v.w;
            }
            part = fmaxf(acc, 0.0f) * l3w[bank * 10 + lane];
        }
        part += __shfl_xor(part, 1);
        part += __shfl_xor(part, 2);
        part += __shfl_xor(part, 4);
        part += __shfl_xor(part, 8);
        float acc3 = __uint_as_float(__builtin_amdgcn_readfirstlane(__float_as_uint(part)))
                   + l3b[bank];
        float sig  = 1.0f / (1.0f + __expf(-acc3));
        float f0v  = (float)D_IN * sig;
        if (lane == 0) outF0[(size_t)bank * BATCH + row] = f0v;

        // ---- filter: stage H in LDS, keep xn (next x_aux) in registers ----
        float4 xn0, xn1, xn2 = {0.f, 0.f, 0.f, 0.f};
        {   // chunk 0: elements 4*lane .. 4*lane+3
            float4 xv = *(const float4*)&xa[4 * lane];
            float d0 = (float)(4 * lane) - f0v;
            float4 Hv;
            Hv.x = __builtin_amdgcn_exp2f(d0 * d0 * negc2);
            Hv.y = __builtin_amdgcn_exp2f((d0 + 1.f) * (d0 + 1.f) * negc2);
            Hv.z = __builtin_amdgcn_exp2f((d0 + 2.f) * (d0 + 2.f) * negc2);
            Hv.w = __builtin_amdgcn_exp2f((d0 + 3.f) * (d0 + 3.f) * negc2);
            *(float4*)&s_oH[wave][4 * lane] = Hv;
            xn0.x = xv.x - xv.x * Hv.x;  xn0.y = xv.y - xv.y * Hv.y;
            xn0.z = xv.z - xv.z * Hv.z;  xn0.w = xv.w - xv.w * Hv.w;
        }
        {   // chunk 1: elements 4*(64+lane) ..
            const int e = 4 * (64 + lane);
            float4 xv = *(const float4*)&xa[e];
            float d0 = (float)e - f0v;
            float4 Hv;
            Hv.x = __builtin_amdgcn_exp2f(d0 * d0 * negc2);
            Hv.y = __builtin_amdgcn_exp2f((d0 + 1.f) * (d0 + 1.f) * negc2);
            Hv.z = __builtin_amdgcn_exp2f((d0 + 2.f) * (d0 + 2.f) * negc2);
            Hv.w = __builtin_amdgcn_exp2f((d0 + 3.f) * (d0 + 3.f) * negc2);
            *(float4*)&s_oH[wave][e] = Hv;
            xn1.x = xv.x - xv.x * Hv.x;  xn1.y = xv.y - xv.y * Hv.y;
            xn1.z = xv.z - xv.z * Hv.z;  xn1.w = xv.w - xv.w * Hv.w;
        }
        if (lane < 20) {  // chunk 2: elements 4*(128+lane) .. (512..591)
            const int e = 4 * (128 + lane);
            float4 xv = *(const float4*)&xa[e];
            float d0 = (float)e - f0v;
            float4 Hv;
            Hv.x = __builtin_amdgcn_exp2f(d0 * d0 * negc2);
            Hv.y = __builtin_amdgcn_exp2f((d0 + 1.f) * (d0 + 1.f) * negc2);
            Hv.z = __builtin_amdgcn_exp2f((d0 + 2.f) * (d0 + 2.f) * negc2);
            Hv.w = __builtin_amdgcn_exp2f((d0 + 3.f) * (d0 + 3.f) * negc2);
            *(float4*)&s_oH[wave][e] = Hv;
            xn2.x = xv.x - xv.x * Hv.x;  xn2.y = xv.y - xv.y * Hv.y;
            xn2.z = xv.z - xv.z * Hv.z;  xn2.w = xv.w - xv.w * Hv.w;
        }
        __syncthreads();   // all waves: s_oH filled, s_xa still pre-update

        // ---- cooperative sweep: 3 monotonic 128B-aligned nt streams/block ----
        {
            const size_t base = ((size_t)bank * BATCH + blkrow) * D_IN;
            const float* xf_ = &s_xa[0][0];
            const float* hf_ = &s_oH[0][0];
            {   const int u = tid;                     // float4 index 0..591
                float4 xv = *(const float4*)&xf_[4 * u];
                float4 hv = *(const float4*)&hf_[4 * u];
                nt_store4((float*)&outXS[base + 4 * u], xv.x, xv.y, xv.z, xv.w);
                nt_store4((float*)&outH [base + 4 * u], hv.x, hv.y, hv.z, hv.w);
                nt_store4((float*)&outXF[base + 4 * u], xv.x * hv.x, xv.y * hv.y,
                                                        xv.z * hv.z, xv.w * hv.w);
            }
            {   const int u = tid + 256;
                float4 xv = *(const float4*)&xf_[4 * u];
                float4 hv = *(const float4*)&hf_[4 * u];
                nt_store4((float*)&outXS[base + 4 * u], xv.x, xv.y, xv.z, xv.w);
                nt_store4((float*)&outH [base + 4 * u], hv.x, hv.y, hv.z, hv.w);
                nt_store4((float*)&outXF[base + 4 * u], xv.x * hv.x, xv.y * hv.y,
                                                        xv.z * hv.z, xv.w * hv.w);
            }
            if (tid < 80) {
                const int u = tid + 512;               // 592 float4 total
                float4 xv = *(const float4*)&xf_[4 * u];
                float4 hv = *(const float4*)&hf_[4 * u];
                nt_store4((float*)&outXS[base + 4 * u], xv.x, xv.y, xv.z, xv.w);
                nt_store4((float*)&outH [base + 4 * u], hv.x, hv.y, hv.z, hv.w);
                nt_store4((float*)&outXF[base + 4 * u], xv.x * hv.x, xv.y * hv.y,
                                                        xv.z * hv.z, xv.w * hv.w);
            }
        }
        __syncthreads();   // sweep done reading s_xa; safe to overwrite

        if (bank < FBANKS - 1) {
            *(float4*)&xa[4 * lane]        = xn0;
            *(float4*)&xa[4 * (64 + lane)] = xn1;
            if (lane < 20)
                *(float4*)&xa[4 * (128 + lane)] = xn2;
        }
        WAVE_SYNC();
    }
}

extern "C" void kernel_launch(void* const* d_in, const int* in_sizes, int n_in,
                              void* d_out, int out_size, void* d_ws, size_t ws_size,
                              hipStream_t stream) {
    const float* x   = (const float*)d_in[0];
    const float* c1w = (const float*)d_in[1];
    const float* c1b = (const float*)d_in[2];
    const float* c2w = (const float*)d_in[3];
    const float* c2b = (const float*)d_in[4];
    const float* l1w = (const float*)d_in[5];
    const float* l1b = (const float*)d_in[6];
    const float* l2w = (const float*)d_in[7];
    const float* l2b = (const float*)d_in[8];
    const float* l3w = (const float*)d_in[9];
    const float* l3b = (const float*)d_in[10];

    float* out = (float*)d_out;
    const size_t plane = (size_t)FBANKS * BATCH * D_IN;
    float* outH  = out;
    float* outXF = out + plane;
    float* outXS = out + 2 * plane;
    float* outF0 = out + 3 * plane;

    dim3 grid(BATCH / NW);
    dim3 block(256);
    fb_kernel<<<grid, block, 0, stream>>>(x, c1w, c1b, c2w, c2b,
                                          l1w, l1b, l2w, l2b, l3w, l3b,
                                          outH, outXF, outXS, outF0);
}